// Round 5
// baseline (147.995 us; speedup 1.0000x reference)
//
#include <hip/hip_runtime.h>

// CuriosityEngine: the goal_sampler path (32x replicated bottleneck + argmax)
// is output-invariant — all 32 action slices are bit-identical, so
// argmax(predicted_entropy) == 0 always. Only the surprise head matters:
//   surprise = relu(mean_T(x).reshape(B,2D) @ W1 + b1) @ W2 + b2   -> (B,)
//   best_action_idx = 0                                            -> scalar
//
// x: (B=4, T=2048, D=768, 2) fp32 => rows of R=1536 floats, reduce over T.
//
// R4 post-mortem: 2-dispatch version still spent ~35 µs (vs ~13 µs floor) on
// the hpart round-trip + dependent-dispatch drain. This version is ONE worker
// kernel: blocks atomicAdd hidden-partials into a 4 KB accumulator, a
// device-scope done-counter elects the last block, which reads hid back via
// atomicAdd(p, 0.0f) (coherent read across XCDs) and finishes the MLP head.

#define BB 4
#define TT 2048
#define RR 1536        // 2*D
#define HH 256
#define NJC 24         // j-chunks (1536/64)
#define JCW 64         // j's per chunk (16 float4)
#define NTC 8          // t-chunks (256 rows each)
#define TCH (TT / NTC)
#define NBLK (NJC * NTC * BB)   // 768

__global__ __launch_bounds__(256) void curiosity_fused_kernel(
        const float* __restrict__ x,  const float* __restrict__ W1,
        const float* __restrict__ b1, const float* __restrict__ W2,
        const float* __restrict__ b2,
        float* __restrict__ hid, unsigned* __restrict__ counter,
        float* __restrict__ out) {
    const int jc  = blockIdx.x;            // 0..NJC-1
    const int tc  = blockIdx.y;            // 0..NTC-1
    const int b   = blockIdx.z;
    const int tid = threadIdx.x;

    __shared__ float4 red4[16][16];        // [rowgrp][col_local]
    __shared__ float  sfl[JCW];            // mean-scaled j-slice
    __shared__ bool   is_last;

    // ---- Phase A: reduce 256 rows of this block's 64-col slice of x ----
    const int rowl  = tid >> 4;            // 0..15
    const int colf4 = tid & 15;            // 0..15
    const float4* xb = (const float4*)(x + (size_t)b * TT * RR);
    const int t0  = tc * TCH;
    const int col = jc * 16 + colf4;
    float4 acc = make_float4(0.f, 0.f, 0.f, 0.f);
    #pragma unroll
    for (int pass = 0; pass < 16; ++pass) {
        const int t = t0 + pass * 16 + rowl;
        float4 v = xb[(size_t)t * (RR / 4) + col];
        acc.x += v.x; acc.y += v.y; acc.z += v.z; acc.w += v.w;
    }
    red4[rowl][colf4] = acc;
    __syncthreads();
    if (tid < 16) {
        float4 s = make_float4(0.f, 0.f, 0.f, 0.f);
        #pragma unroll
        for (int r = 0; r < 16; ++r) {
            float4 v = red4[r][tid];
            s.x += v.x; s.y += v.y; s.z += v.z; s.w += v.w;
        }
        const float inv_t = 1.0f / (float)TT;
        sfl[tid * 4 + 0] = s.x * inv_t;
        sfl[tid * 4 + 1] = s.y * inv_t;
        sfl[tid * 4 + 2] = s.z * inv_t;
        sfl[tid * 4 + 3] = s.w * inv_t;
    }
    __syncthreads();

    // ---- Phase B: GEMV slice, thread == h; W1 coalesced, sfl broadcast ----
    const int jbase = jc * JCW;
    float hacc = 0.f;
    #pragma unroll 8
    for (int j = 0; j < JCW; ++j) {
        hacc += sfl[j] * W1[(size_t)(jbase + j) * HH + tid];
    }
    // 192 blocks contend per address; fp32 atomics pipeline across the
    // 1024 distinct addresses (device-scope by default — cross-XCD safe).
    atomicAdd(&hid[b * HH + tid], hacc);

    // ---- Phase C: elect last block ----
    __threadfence();                       // release hid update
    if (tid == 0) {
        unsigned old = atomicAdd(counter, 1u);
        is_last = (old == NBLK - 1);
    }
    __syncthreads();
    if (!is_last) return;

    // ---- Phase D (last block only): MLP head for all batches ----
    // Read hid through the atomic path: coherent regardless of which XCD's
    // L2 holds what. 4 independent reads/thread — latency pipelined.
    float v[BB];
    const float b1v = b1[tid];
    const float w2v = W2[tid];
    #pragma unroll
    for (int bb = 0; bb < BB; ++bb) {
        float hv = atomicAdd(&hid[bb * HH + tid], 0.0f);
        float t = fmaxf(hv + b1v, 0.f) * w2v;
        #pragma unroll
        for (int off = 32; off > 0; off >>= 1) t += __shfl_down(t, off, 64);
        v[bb] = t;                          // valid in lane 0 of each wave
    }
    __shared__ float red[4][BB];            // [wave][b]
    const int lane = tid & 63, wave = tid >> 6;
    if (lane == 0) {
        #pragma unroll
        for (int bb = 0; bb < BB; ++bb) red[wave][bb] = v[bb];
    }
    __syncthreads();
    if (tid < BB) {
        out[tid] = red[0][tid] + red[1][tid] + red[2][tid] + red[3][tid] + b2[0];
    }
    if (tid == 0) {
        // best_action_idx: argmax over 32 bit-identical entropies == 0.
        // 0x00000000 is valid under either f32 or i32 readback.
        out[BB] = 0.0f;
    }
}

extern "C" void kernel_launch(void* const* d_in, const int* in_sizes, int n_in,
                              void* d_out, int out_size, void* d_ws, size_t ws_size,
                              hipStream_t stream) {
    const float* x  = (const float*)d_in[0];
    const float* W1 = (const float*)d_in[1];
    const float* b1 = (const float*)d_in[2];
    const float* W2 = (const float*)d_in[3];
    const float* b2 = (const float*)d_in[4];
    // d_in[5..8] (Wd, bd, Wu, bu) unused: bottleneck path is output-invariant.

    float*    hid     = (float*)d_ws;              // BB*HH fp32 accumulator
    unsigned* counter = (unsigned*)(hid + BB * HH);

    // ws is poisoned (0xAA before timed launches; unknown on the correctness
    // call) — zero the 4.1 KB we actually use. Tiny fill, one dispatch.
    hipMemsetAsync(d_ws, 0, BB * HH * sizeof(float) + sizeof(unsigned), stream);

    curiosity_fused_kernel<<<dim3(NJC, NTC, BB), 256, 0, stream>>>(
        x, W1, b1, W2, b2, hid, counter, (float*)d_out);
}